// Round 1
// baseline (76.427 us; speedup 1.0000x reference)
//
#include <hip/hip_runtime.h>

#define NQ    10
#define DIM   1024
#define NL    5
#define NPAIR 45
#define NX    55   // NQ + NPAIR

// new_me = c*me - i*s*other   (works for BOTH halves of an RX butterfly)
__device__ __forceinline__ float2 rotg(float2 me, float ox, float oy, float c, float s) {
    return make_float2(fmaf(c, me.x,  s * oy),
                       fmaf(c, me.y, -s * ox));
}

__global__ __launch_bounds__(256, 2)
void ppo_quantum_kernel(const float* __restrict__ x,        // (B,55)
                        const float* __restrict__ isa,      // (5,)
                        const float* __restrict__ wa,       // (5,)
                        const float* __restrict__ osa,      // (10,)
                        const float* __restrict__ isc,      // (5,)
                        const float* __restrict__ wc,       // (5,)
                        const float* __restrict__ osc,      // (1,)
                        const int*   __restrict__ action,   // (B,)
                        float* __restrict__ out)            // (B,3)
{
    const int b    = blockIdx.x;
    const int t    = threadIdx.x;      // 0..255 ; index bits 0..7
    const int lane = t & 63;
    const int wave = t >> 6;

    __shared__ float2 xch[DIM];        // 8 KB exchange buffer for qubit 2,3 gates
    __shared__ float  xrow[NX];
    __shared__ float  red[4][NQ];
    __shared__ float  expv_a[NQ];
    __shared__ float  expv_c[NQ];

    if (t < NX) xrow[t] = x[b * NX + t];
    __syncthreads();

    // ---- expo[d] = sum_q h_q * z_q(d) + sum_(i<j) J_ij * z_i(d) * z_j(d) ----
    // z_q(d) = 1 - 2*((d >> (9-q)) & 1)
    float expo[4];
#pragma unroll
    for (int r = 0; r < 4; ++r) {
        const int d = (r << 8) | t;
        float e = 0.f;
#pragma unroll
        for (int q = 0; q < NQ; ++q) {
            unsigned sm = ((unsigned)((d >> (9 - q)) & 1)) << 31;
            e += __uint_as_float(__float_as_uint(xrow[q]) ^ sm);
        }
        int p = NQ;
#pragma unroll
        for (int i = 0; i < NQ; ++i) {
#pragma unroll
            for (int j = i + 1; j < NQ; ++j) {
                unsigned sm = ((unsigned)(((d >> (9 - i)) ^ (d >> (9 - j))) & 1)) << 31;
                e += __uint_as_float(__float_as_uint(xrow[p]) ^ sm);
                ++p;
            }
        }
        expo[r] = e;
    }

    // ---- two circuits: 0 = actor, 1 = critic ----
    for (int circ = 0; circ < 2; ++circ) {
        const float* iscale = circ ? isc : isa;
        const float* wts    = circ ? wc  : wa;

        float2 a[4];
#pragma unroll
        for (int r = 0; r < 4; ++r) a[r] = make_float2(0.03125f, 0.f);  // 1/sqrt(1024)

        for (int l = 0; l < NL; ++l) {
            const float sl = iscale[l];
            float c, s;
            __sincosf(0.5f * wts[l], &s, &c);

            // diagonal phase: a *= exp(-0.5i * sl * expo)
#pragma unroll
            for (int r = 0; r < 4; ++r) {
                float sn, cs;
                __sincosf(-0.5f * sl * expo[r], &sn, &cs);
                const float re = a[r].x, im = a[r].y;
                a[r].x = re * cs - im * sn;
                a[r].y = re * sn + im * cs;
            }

            // qubit 0 (bit 9): pairs (r, r^2) -- register gate
            {
                float2 t0 = a[0], t1 = a[1], t2 = a[2], t3 = a[3];
                a[0] = rotg(t0, t2.x, t2.y, c, s);
                a[1] = rotg(t1, t3.x, t3.y, c, s);
                a[2] = rotg(t2, t0.x, t0.y, c, s);
                a[3] = rotg(t3, t1.x, t1.y, c, s);
            }
            // qubit 1 (bit 8): pairs (r, r^1) -- register gate
            {
                float2 t0 = a[0], t1 = a[1], t2 = a[2], t3 = a[3];
                a[0] = rotg(t0, t1.x, t1.y, c, s);
                a[1] = rotg(t1, t0.x, t0.y, c, s);
                a[2] = rotg(t2, t3.x, t3.y, c, s);
                a[3] = rotg(t3, t2.x, t2.y, c, s);
            }
            // qubits 2,3 (bits 7,6): cross-wave -> LDS exchange
#pragma unroll
            for (int mb = 7; mb >= 6; --mb) {
                const int mask = 1 << mb;
                __syncthreads();                       // prior reads of xch done
#pragma unroll
                for (int r = 0; r < 4; ++r) xch[(r << 8) | t] = a[r];
                __syncthreads();
#pragma unroll
                for (int r = 0; r < 4; ++r) {
                    const float2 o = xch[(r << 8) | (t ^ mask)];
                    a[r] = rotg(a[r], o.x, o.y, c, s);
                }
            }
            // qubits 4..9 (bits 5..0): in-wave shuffles
#pragma unroll
            for (int sh = 5; sh >= 0; --sh) {
                const int mask = 1 << sh;
#pragma unroll
                for (int r = 0; r < 4; ++r) {
                    const float ox = __shfl_xor(a[r].x, mask);
                    const float oy = __shfl_xor(a[r].y, mask);
                    a[r] = rotg(a[r], ox, oy, c, s);
                }
            }
        }

        // ---- expectation values <Z_q> = sum_d |a_d|^2 * z_q(d) ----
        float p0 = a[0].x * a[0].x + a[0].y * a[0].y;
        float p1 = a[1].x * a[1].x + a[1].y * a[1].y;
        float p2 = a[2].x * a[2].x + a[2].y * a[2].y;
        float p3 = a[3].x * a[3].x + a[3].y * a[3].y;

        const float s01 = p0 + p1, s23 = p2 + p3;
        const float s02 = p0 + p2, s13 = p1 + p3;
        const float tot = s01 + s23;

        float v[NQ];
        v[0] = s01 - s23;    // qubit 0: bit9 = r>>1
        v[1] = s02 - s13;    // qubit 1: bit8 = r&1
#pragma unroll
        for (int q = 2; q < NQ; ++q)
            v[q] = ((t >> (9 - q)) & 1) ? -tot : tot;

        // 6-stage wave butterfly for all 10 sums
#pragma unroll
        for (int sh = 1; sh <= 32; sh <<= 1) {
#pragma unroll
            for (int q = 0; q < NQ; ++q)
                v[q] += __shfl_xor(v[q], sh);
        }
        if (lane == 0) {
#pragma unroll
            for (int q = 0; q < NQ; ++q) red[wave][q] = v[q];
        }
        __syncthreads();
        float* ev = circ ? expv_c : expv_a;
        if (t < NQ) ev[t] = red[0][t] + red[1][t] + red[2][t] + red[3][t];
        __syncthreads();
    }

    // ---- epilogue: log_softmax(actor), entropy, value ----
    if (t == 0) {
        float logits[NQ];
        float m = -1e30f;
#pragma unroll
        for (int q = 0; q < NQ; ++q) {
            logits[q] = expv_a[q] * osa[q];
            m = fmaxf(m, logits[q]);
        }
        float se = 0.f;
#pragma unroll
        for (int q = 0; q < NQ; ++q) se += expf(logits[q] - m);
        const float lse = logf(se) + m;

        float ent = 0.f;
#pragma unroll
        for (int q = 0; q < NQ; ++q) {
            const float lp = logits[q] - lse;
            ent -= expf(lp) * lp;
        }
        const int act = action[b];
        out[b * 3 + 0] = logits[act] - lse;
        out[b * 3 + 1] = ent;
        out[b * 3 + 2] = expv_c[0] * osc[0];
    }
}

extern "C" void kernel_launch(void* const* d_in, const int* in_sizes, int n_in,
                              void* d_out, int out_size, void* d_ws, size_t ws_size,
                              hipStream_t stream) {
    const float* x      = (const float*)d_in[0];
    const float* isa    = (const float*)d_in[1];
    const float* wa     = (const float*)d_in[2];
    const float* osa    = (const float*)d_in[3];
    const float* isc    = (const float*)d_in[4];
    const float* wc     = (const float*)d_in[5];
    const float* osc    = (const float*)d_in[6];
    const int*   action = (const int*)d_in[7];
    float*       out    = (float*)d_out;

    const int B = in_sizes[7];   // action has one entry per batch element

    ppo_quantum_kernel<<<B, 256, 0, stream>>>(x, isa, wa, osa, isc, wc, osc, action, out);
}

// Round 2
// 55.665 us; speedup vs baseline: 1.3730x; 1.3730x over previous
//
#include <hip/hip_runtime.h>

#define NQ 10
#define NL 5
#define NX 55   // 10 singles + 45 pair couplings

// flip sign of v iff bit==1
__device__ __forceinline__ float sflip(float v, unsigned bit) {
    return __uint_as_float(__float_as_uint(v) ^ (bit << 31));
}
// new_me = c*me - i*s*other  (both halves of an RX butterfly)
__device__ __forceinline__ float2 rotg(float2 me, float ox, float oy, float c, float s) {
    return make_float2(fmaf(c, me.x,  s * oy),
                       fmaf(c, me.y, -s * ox));
}

__global__ __launch_bounds__(256, 4)
void ppo_quantum_kernel(const float* __restrict__ x,        // (B,55)
                        const float* __restrict__ isa,      // (5,)
                        const float* __restrict__ wa,       // (5,)
                        const float* __restrict__ osa,      // (10,)
                        const float* __restrict__ isc,      // (5,)
                        const float* __restrict__ wc,       // (5,)
                        const float* __restrict__ osc,      // (1,)
                        const int*   __restrict__ action,   // (B,)
                        float* __restrict__ out)            // (B,3)
{
    const int t    = threadIdx.x;
    const int wave = t >> 6;           // 4 waves/block
    const int lane = t & 63;
    const int elem = blockIdx.x * 2 + (wave >> 1);   // 2 elements per block
    const int circ = wave & 1;                       // 0 = actor, 1 = critic

    // stage the two x-rows for this block (broadcast reads later)
    __shared__ float sx[2][NX];
    if (t < 2 * NX) sx[t / NX][t % NX] = x[blockIdx.x * 2 * NX + t];
    __syncthreads();                                  // the ONLY barrier
    const float* xr = sx[wave >> 1];

    // amplitude index d = (r<<6) | lane, r = 0..15
    // qubit q acts on d-bit (9-q): q=0..3 -> r bits 3..0 (register gates)
    //                              q=4..9 -> lane bits 5..0 (shuffle gates)

    // ---- expo decomposition ----
    unsigned lb[6];                                   // lane bit for qubit 4..9
#pragma unroll
    for (int q = 4; q < 10; ++q) lb[q - 4] = (lane >> (9 - q)) & 1;

    // lane-only part: low singles + low-low pairs (p = 40..54)
    float L = 0.f;
#pragma unroll
    for (int q = 4; q < 10; ++q) L += sflip(xr[q], lb[q - 4]);
    {
        int p = 40;
#pragma unroll
        for (int i = 4; i < 10; ++i)
#pragma unroll
            for (int j = i + 1; j < 10; ++j)
                L += sflip(xr[p++], lb[i - 4] ^ lb[j - 4]);
    }
    // cross sums: T[i] = h_i + sum_j J_ij * z_j(lane),  i = 0..3, j = 4..9
    float T[4];
#pragma unroll
    for (int i = 0; i < 4; ++i) {
        const int pb = (i == 0 ? 13 : i == 1 ? 21 : i == 2 ? 28 : 34);
        float acc = xr[i];
#pragma unroll
        for (int j = 4; j < 10; ++j) acc += sflip(xr[pb + (j - 4)], lb[j - 4]);
        T[i] = acc;
    }
    const float J01 = xr[10], J02 = xr[11], J03 = xr[12];
    const float J12 = xr[19], J13 = xr[20], J23 = xr[27];

    float expo[16];
#pragma unroll
    for (int r = 0; r < 16; ++r) {
        const unsigned b0 = (r >> 3) & 1, b1 = (r >> 2) & 1,
                       b2 = (r >> 1) & 1, b3 = r & 1;
        float e = L;
        e += sflip(T[0], b0);  e += sflip(T[1], b1);
        e += sflip(T[2], b2);  e += sflip(T[3], b3);
        e += sflip(J01, b0 ^ b1); e += sflip(J02, b0 ^ b2); e += sflip(J03, b0 ^ b3);
        e += sflip(J12, b1 ^ b2); e += sflip(J13, b1 ^ b3); e += sflip(J23, b2 ^ b3);
        expo[r] = e;
    }

    // ---- simulate this wave's circuit ----
    const float* iscale = circ ? isc : isa;
    const float* wts    = circ ? wc  : wa;

    float2 a[16];
#pragma unroll
    for (int r = 0; r < 16; ++r) a[r] = make_float2(0.03125f, 0.f); // 1/sqrt(1024)

    for (int l = 0; l < NL; ++l) {
        const float m = -0.5f * iscale[l];
        float c, s;
        __sincosf(0.5f * wts[l], &s, &c);

        // diagonal phase
#pragma unroll
        for (int r = 0; r < 16; ++r) {
            float sn, cs;
            __sincosf(m * expo[r], &sn, &cs);
            const float re = a[r].x, im = a[r].y;
            a[r].x = fmaf(re, cs, -im * sn);
            a[r].y = fmaf(re, sn,  im * cs);
        }
        // register gates (qubits 0..3 -> r-bit masks 8,4,2,1)
#pragma unroll
        for (int g = 0; g < 4; ++g) {
            const int qm = 8 >> g;
#pragma unroll
            for (int r = 0; r < 16; ++r) {
                if (!(r & qm)) {
                    const float2 lo = a[r], hi = a[r | qm];
                    a[r]      = rotg(lo, hi.x, hi.y, c, s);
                    a[r | qm] = rotg(hi, lo.x, lo.y, c, s);
                }
            }
        }
        // lane gates (qubits 4..9 -> lane masks 32..1)
#pragma unroll
        for (int g = 0; g < 6; ++g) {
            const int lm = 32 >> g;
#pragma unroll
            for (int r = 0; r < 16; ++r) {
                const float ox = __shfl_xor(a[r].x, lm);
                const float oy = __shfl_xor(a[r].y, lm);
                a[r] = rotg(a[r], ox, oy, c, s);
            }
        }
    }

    // ---- probabilities ----
    float p[16];
#pragma unroll
    for (int r = 0; r < 16; ++r) p[r] = a[r].x * a[r].x + a[r].y * a[r].y;

    if (circ == 0) {
        // actor: all 10 <Z_q>
        float v[10];
#pragma unroll
        for (int q = 0; q < 4; ++q) {
            const int qm = 8 >> q;
            float acc = 0.f;
#pragma unroll
            for (int r = 0; r < 16; ++r) acc += (r & qm) ? -p[r] : p[r];
            v[q] = acc;
        }
        float tot = 0.f;
#pragma unroll
        for (int r = 0; r < 16; ++r) tot += p[r];
#pragma unroll
        for (int q = 4; q < 10; ++q) v[q] = sflip(tot, lb[q - 4]);

#pragma unroll
        for (int sh = 1; sh <= 32; sh <<= 1)
#pragma unroll
            for (int q = 0; q < 10; ++q) v[q] += __shfl_xor(v[q], sh);

        // epilogue computed redundantly on all lanes (no divergence)
        float logits[10], mx = -1e30f;
#pragma unroll
        for (int q = 0; q < 10; ++q) {
            logits[q] = v[q] * osa[q];
            mx = fmaxf(mx, logits[q]);
        }
        float se = 0.f;
#pragma unroll
        for (int q = 0; q < 10; ++q) se += __expf(logits[q] - mx);
        const float lse = __logf(se) + mx;
        float ent = 0.f;
#pragma unroll
        for (int q = 0; q < 10; ++q) {
            const float lp = logits[q] - lse;
            ent -= __expf(lp) * lp;
        }
        if (lane == 0) {
            const int act = action[elem];
            out[elem * 3 + 0] = logits[act] - lse;
            out[elem * 3 + 1] = ent;
        }
    } else {
        // critic: only <Z_0> (r-bit 3)
        float v0 = 0.f;
#pragma unroll
        for (int r = 0; r < 16; ++r) v0 += (r & 8) ? -p[r] : p[r];
#pragma unroll
        for (int sh = 1; sh <= 32; sh <<= 1) v0 += __shfl_xor(v0, sh);
        if (lane == 0) out[elem * 3 + 2] = v0 * osc[0];
    }
}

extern "C" void kernel_launch(void* const* d_in, const int* in_sizes, int n_in,
                              void* d_out, int out_size, void* d_ws, size_t ws_size,
                              hipStream_t stream) {
    const float* x      = (const float*)d_in[0];
    const float* isa    = (const float*)d_in[1];
    const float* wa     = (const float*)d_in[2];
    const float* osa    = (const float*)d_in[3];
    const float* isc    = (const float*)d_in[4];
    const float* wc     = (const float*)d_in[5];
    const float* osc    = (const float*)d_in[6];
    const int*   action = (const int*)d_in[7];
    float*       out    = (float*)d_out;

    const int B = in_sizes[7];
    // one wave per (element, circuit): 4 waves/block -> 2 elements/block
    ppo_quantum_kernel<<<B / 2, 256, 0, stream>>>(x, isa, wa, osa, isc, wc, osc,
                                                  action, out);
}

// Round 5
// 46.695 us; speedup vs baseline: 1.6367x; 1.1921x over previous
//
#include <hip/hip_runtime.h>

#define NL 5

// flip sign of v iff bit==1
__device__ __forceinline__ float sflip(float v, unsigned bit) {
    return __uint_as_float(__float_as_uint(v) ^ (bit << 31));
}
// new_me = c*me - i*s*other  (both halves of an RX butterfly)
__device__ __forceinline__ float2 rotg(float2 me, float ox, float oy, float c, float s) {
    return make_float2(fmaf(c, me.x,  s * oy),
                       fmaf(c, me.y, -s * ox));
}
// cross-lane via DPP quad_perm (VALU pipe, not LDS): CTRL=0xB1 -> lane^1, 0x4E -> lane^2
template <int CTRL>
__device__ __forceinline__ float dppx(float v) {
    return __int_as_float(__builtin_amdgcn_update_dpp(
        0, __float_as_int(v), CTRL, 0xF, 0xF, true));
}

__global__ __launch_bounds__(128, 8)
void ppo_quantum_kernel(const float* __restrict__ x,        // (B,55)
                        const float* __restrict__ isa,      // (5,)
                        const float* __restrict__ wa,       // (5,)
                        const float* __restrict__ osa,      // (10,)
                        const float* __restrict__ isc,      // (5,)
                        const float* __restrict__ wc,       // (5,)
                        const float* __restrict__ osc,      // (1,)
                        const int*   __restrict__ action,   // (B,)
                        float* __restrict__ out)            // (B,3)
{
    const int t    = threadIdx.x;      // 128 threads = 2 waves
    const int w    = t >> 6;           // wave bit = amplitude bit d9 (qubit 0)
    const int lane = t & 63;           // lane bits = d5..d0 (qubits 4..9)
    const int elem = blockIdx.x >> 1;
    const int circ = blockIdx.x & 1;   // 0 = actor, 1 = critic
    const float* __restrict__ xr = x + elem * 55;   // uniform -> scalar loads

    __shared__ float2 xch[8][2][64];   // 8 KB exchange for the qubit-0 gate
    __shared__ float  red[2][10];

    // amplitude index d = (w<<9) | (r<<6) | lane, r = 0..7 (bits d8,d7,d6 = qubits 1..3)
    unsigned lb[6];                    // lane bit of qubit 4+k  (d-bit 5-k)
#pragma unroll
    for (int k = 0; k < 6; ++k) lb[k] = (lane >> (5 - k)) & 1u;

    // ---- expo decomposition ----
    float L = 0.f;                     // lane-only: singles 4..9 + pairs among them
#pragma unroll
    for (int k = 0; k < 6; ++k) L += sflip(xr[4 + k], lb[k]);
    {
        int p = 40;                    // J_ij for i,j in 4..9 sits at x[40..54]
#pragma unroll
        for (int i = 0; i < 6; ++i)
#pragma unroll
            for (int j = i + 1; j < 6; ++j)
                L += sflip(xr[p++], lb[i] ^ lb[j]);
    }
    float T0 = xr[0], T1 = xr[1], T2 = xr[2], T3 = xr[3];
#pragma unroll
    for (int k = 0; k < 6; ++k) {      // cross terms J_{i,4..9}
        T0 += sflip(xr[13 + k], lb[k]);
        T1 += sflip(xr[21 + k], lb[k]);
        T2 += sflip(xr[28 + k], lb[k]);
        T3 += sflip(xr[34 + k], lb[k]);
    }
    const unsigned uw = (unsigned)w;
    T0 = sflip(T0, uw);                // fold wave bit (z_0) into T0 and J_0x
    const float J01 = sflip(xr[10], uw), J02 = sflip(xr[11], uw), J03 = sflip(xr[12], uw);
    const float J12 = xr[19], J13 = xr[20], J23 = xr[27];

    float expo[8];
#pragma unroll
    for (int r = 0; r < 8; ++r) {
        const unsigned b1 = (r >> 2) & 1u, b2 = (r >> 1) & 1u, b3 = r & 1u;
        float e = L + T0;
        e += sflip(T1, b1);      e += sflip(T2, b2);      e += sflip(T3, b3);
        e += sflip(J01, b1);     e += sflip(J02, b2);     e += sflip(J03, b3);
        e += sflip(J12, b1 ^ b2); e += sflip(J13, b1 ^ b3); e += sflip(J23, b2 ^ b3);
        expo[r] = e;
    }

    // ---- simulate this block's circuit ----
    const float* iscale = circ ? isc : isa;
    const float* wts    = circ ? wc  : wa;

    float2 a[8];
#pragma unroll
    for (int r = 0; r < 8; ++r) a[r] = make_float2(0.03125f, 0.f);  // 1/sqrt(1024)

#pragma unroll
    for (int l = 0; l < NL; ++l) {
        const float m = -0.5f * iscale[l];
        float c, s;
        __sincosf(0.5f * wts[l], &s, &c);

        // diagonal phase
#pragma unroll
        for (int r = 0; r < 8; ++r) {
            float sn, cs;
            __sincosf(m * expo[r], &sn, &cs);
            const float re = a[r].x, im = a[r].y;
            a[r].x = fmaf(re, cs, -im * sn);
            a[r].y = fmaf(re, sn,  im * cs);
        }

        // qubit 0 (wave bit): LDS exchange with the partner wave
        __syncthreads();                         // prior reads of xch done
#pragma unroll
        for (int r = 0; r < 8; ++r) xch[r][w][lane] = a[r];
        __syncthreads();
#pragma unroll
        for (int r = 0; r < 8; ++r) {
            const float2 o = xch[r][w ^ 1][lane];
            a[r] = rotg(a[r], o.x, o.y, c, s);
        }

        // qubits 1..3: register butterflies (r-bit masks 4,2,1)
#pragma unroll
        for (int g = 0; g < 3; ++g) {
            const int qm = 4 >> g;
#pragma unroll
            for (int r = 0; r < 8; ++r)
                if (!(r & qm)) {
                    const float2 lo = a[r], hi = a[r | qm];
                    a[r]      = rotg(lo, hi.x, hi.y, c, s);
                    a[r | qm] = rotg(hi, lo.x, lo.y, c, s);
                }
        }

        // qubits 4..7: lane shuffles (masks 32,16,8,4 -> ds_swizzle)
#pragma unroll
        for (int g = 0; g < 4; ++g) {
            const int lm = 32 >> g;
#pragma unroll
            for (int r = 0; r < 8; ++r) {
                const float ox = __shfl_xor(a[r].x, lm);
                const float oy = __shfl_xor(a[r].y, lm);
                a[r] = rotg(a[r], ox, oy, c, s);
            }
        }
        // qubit 8 (lane^2) and qubit 9 (lane^1): DPP quad_perm on the VALU pipe
#pragma unroll
        for (int r = 0; r < 8; ++r) {
            const float ox = dppx<0x4E>(a[r].x);
            const float oy = dppx<0x4E>(a[r].y);
            a[r] = rotg(a[r], ox, oy, c, s);
        }
#pragma unroll
        for (int r = 0; r < 8; ++r) {
            const float ox = dppx<0xB1>(a[r].x);
            const float oy = dppx<0xB1>(a[r].y);
            a[r] = rotg(a[r], ox, oy, c, s);
        }
    }

    // ---- probabilities & expectation values ----
    float p[8];
#pragma unroll
    for (int r = 0; r < 8; ++r) p[r] = a[r].x * a[r].x + a[r].y * a[r].y;
    float tot = 0.f;
#pragma unroll
    for (int r = 0; r < 8; ++r) tot += p[r];

    if (circ == 0) {
        float v[10];
        v[0] = sflip(tot, uw);                                        // qubit 0: wave bit
        v[1] = (p[0] + p[1] + p[2] + p[3]) - (p[4] + p[5] + p[6] + p[7]);   // r bit 2
        v[2] = (p[0] + p[1] + p[4] + p[5]) - (p[2] + p[3] + p[6] + p[7]);   // r bit 1
        v[3] = (p[0] + p[2] + p[4] + p[6]) - (p[1] + p[3] + p[5] + p[7]);   // r bit 0
#pragma unroll
        for (int k = 0; k < 6; ++k) v[4 + k] = sflip(tot, lb[k]);

#pragma unroll
        for (int sh = 1; sh <= 32; sh <<= 1)
#pragma unroll
            for (int q = 0; q < 10; ++q) v[q] += __shfl_xor(v[q], sh);

        if (lane == 0)
#pragma unroll
            for (int q = 0; q < 10; ++q) red[w][q] = v[q];
        __syncthreads();

        // epilogue computed redundantly on all threads, thread 0 stores
        float logits[10], mx = -1e30f;
#pragma unroll
        for (int q = 0; q < 10; ++q) {
            logits[q] = (red[0][q] + red[1][q]) * osa[q];
            mx = fmaxf(mx, logits[q]);
        }
        float se = 0.f;
#pragma unroll
        for (int q = 0; q < 10; ++q) se += __expf(logits[q] - mx);
        const float lse = __logf(se) + mx;
        float ent = 0.f;
#pragma unroll
        for (int q = 0; q < 10; ++q) {
            const float lp = logits[q] - lse;
            ent -= __expf(lp) * lp;
        }
        if (t == 0) {
            const int act = action[elem];
            out[elem * 3 + 0] = logits[act] - lse;
            out[elem * 3 + 1] = ent;
        }
    } else {
        float v0 = sflip(tot, uw);
#pragma unroll
        for (int sh = 1; sh <= 32; sh <<= 1) v0 += __shfl_xor(v0, sh);
        if (lane == 0) red[w][0] = v0;
        __syncthreads();
        if (t == 0) out[elem * 3 + 2] = (red[0][0] + red[1][0]) * osc[0];
    }
}

extern "C" void kernel_launch(void* const* d_in, const int* in_sizes, int n_in,
                              void* d_out, int out_size, void* d_ws, size_t ws_size,
                              hipStream_t stream) {
    const float* x      = (const float*)d_in[0];
    const float* isa    = (const float*)d_in[1];
    const float* wa     = (const float*)d_in[2];
    const float* osa    = (const float*)d_in[3];
    const float* isc    = (const float*)d_in[4];
    const float* wc     = (const float*)d_in[5];
    const float* osc    = (const float*)d_in[6];
    const int*   action = (const int*)d_in[7];
    float*       out    = (float*)d_out;

    const int B = in_sizes[7];
    // one (elem, circuit) per 128-thread block -> 2*B blocks = 8192 waves
    ppo_quantum_kernel<<<B * 2, 128, 0, stream>>>(x, isa, wa, osa, isc, wc, osc,
                                                  action, out);
}

// Round 6
// 36.769 us; speedup vs baseline: 2.0786x; 1.2700x over previous
//
#include <hip/hip_runtime.h>

#define NL 5

// flip sign of v iff bit==1
__device__ __forceinline__ float sflip(float v, unsigned bit) {
    return __uint_as_float(__float_as_uint(v) ^ (bit << 31));
}
// new_me = c*me - i*s*other  (both halves of an RX butterfly)
__device__ __forceinline__ float2 rotg(float2 me, float ox, float oy, float c, float s) {
    return make_float2(fmaf(c, me.x,  s * oy),
                       fmaf(c, me.y, -s * ox));
}
// DPP cross-lane on the VALU pipe.
//   0xB1 = quad_perm [1,0,3,2]  -> lane^1
//   0x4E = quad_perm [2,3,0,1]  -> lane^2
//   0x1B = quad_perm [3,2,1,0]  -> lane^3
//   0x141 = row_half_mirror     -> lane^7 (within 8)
//   0x128 = row_ror:8           -> lane^8 (rotate by 8 within 16 == xor 8)
template <int CTRL>
__device__ __forceinline__ float dppx(float v) {
    return __int_as_float(__builtin_amdgcn_update_dpp(
        0, __float_as_int(v), CTRL, 0xF, 0xF, true));
}
// data from lane^4 = (^7) then (^3)
__device__ __forceinline__ float dpp_x4(float v) { return dppx<0x1B>(dppx<0x141>(v)); }

// all-lanes butterfly sum across the 64-lane wave (4 DPP stages + 2 swizzle stages)
__device__ __forceinline__ float wave_sum(float v) {
    v += dppx<0xB1>(v);
    v += dppx<0x4E>(v);
    v += dpp_x4(v);
    v += dppx<0x128>(v);
    v += __shfl_xor(v, 16);
    v += __shfl_xor(v, 32);
    return v;
}

__global__ __launch_bounds__(128, 4)
void ppo_quantum_kernel(const float* __restrict__ x,        // (B,55)
                        const float* __restrict__ isa,      // (5,)
                        const float* __restrict__ wa,       // (5,)
                        const float* __restrict__ osa,      // (10,)
                        const float* __restrict__ isc,      // (5,)
                        const float* __restrict__ wc,       // (5,)
                        const float* __restrict__ osc,      // (1,)
                        const int*   __restrict__ action,   // (B,)
                        float* __restrict__ out)            // (B,3)
{
    const int t    = threadIdx.x;      // 128 threads = 2 INDEPENDENT waves
    const int circ = t >> 6;           // wave 0 = actor, wave 1 = critic (same elem)
    const int lane = t & 63;
    const int elem = blockIdx.x;
    const float* __restrict__ xr = x + elem * 55;   // wave-uniform -> scalar loads

    // amplitude index d = (r<<6) | lane, r = 0..15
    // qubit q acts on d-bit (9-q): q0..q3 -> r bits 3..0 (register gates)
    //                              q4..q9 -> lane bits 5..0 (masks 32,16,8,4,2,1)
    unsigned lb[6];                    // lane bit of qubit 4+k
#pragma unroll
    for (int k = 0; k < 6; ++k) lb[k] = (lane >> (5 - k)) & 1u;

    // ---- expo decomposition ----
    float L = 0.f;                     // lane-only: singles 4..9 + pairs among them
#pragma unroll
    for (int k = 0; k < 6; ++k) L += sflip(xr[4 + k], lb[k]);
    {
        int p = 40;                    // J_ij for i,j in 4..9 at x[40..54]
#pragma unroll
        for (int i = 0; i < 6; ++i)
#pragma unroll
            for (int j = i + 1; j < 6; ++j)
                L += sflip(xr[p++], lb[i] ^ lb[j]);
    }
    float T0 = xr[0], T1 = xr[1], T2 = xr[2], T3 = xr[3];
#pragma unroll
    for (int k = 0; k < 6; ++k) {      // cross terms J_{i,4..9}
        T0 += sflip(xr[13 + k], lb[k]);
        T1 += sflip(xr[21 + k], lb[k]);
        T2 += sflip(xr[28 + k], lb[k]);
        T3 += sflip(xr[34 + k], lb[k]);
    }
    const float J01 = xr[10], J02 = xr[11], J03 = xr[12];
    const float J12 = xr[19], J13 = xr[20], J23 = xr[27];

    float expo[16];
#pragma unroll
    for (int r = 0; r < 16; ++r) {
        const unsigned b0 = (r >> 3) & 1u, b1 = (r >> 2) & 1u,
                       b2 = (r >> 1) & 1u, b3 = r & 1u;
        float e = L;
        e += sflip(T0, b0);       e += sflip(T1, b1);
        e += sflip(T2, b2);       e += sflip(T3, b3);
        e += sflip(J01, b0 ^ b1); e += sflip(J02, b0 ^ b2); e += sflip(J03, b0 ^ b3);
        e += sflip(J12, b1 ^ b2); e += sflip(J13, b1 ^ b3); e += sflip(J23, b2 ^ b3);
        expo[r] = e;
    }

    // ---- simulate this wave's circuit ----
    const float* iscale = circ ? isc : isa;
    const float* wts    = circ ? wc  : wa;

    float2 a[16];
#pragma unroll
    for (int r = 0; r < 16; ++r) a[r] = make_float2(0.03125f, 0.f);  // 1/sqrt(1024)

#pragma unroll 1                       // keep body ~8KB, inside I-cache
    for (int l = 0; l < NL; ++l) {
        const float m = -0.5f * iscale[l];
        float c, s;
        __sincosf(0.5f * wts[l], &s, &c);

        // diagonal phase
#pragma unroll
        for (int r = 0; r < 16; ++r) {
            float sn, cs;
            __sincosf(m * expo[r], &sn, &cs);
            const float re = a[r].x, im = a[r].y;
            a[r].x = fmaf(re, cs, -im * sn);
            a[r].y = fmaf(re, sn,  im * cs);
        }

        // qubits 0..3: register butterflies (r-bit masks 8,4,2,1)
#pragma unroll
        for (int g = 0; g < 4; ++g) {
            const int qm = 8 >> g;
#pragma unroll
            for (int r = 0; r < 16; ++r)
                if (!(r & qm)) {
                    const float2 lo = a[r], hi = a[r | qm];
                    a[r]      = rotg(lo, hi.x, hi.y, c, s);
                    a[r | qm] = rotg(hi, lo.x, lo.y, c, s);
                }
        }

        // qubit 4: lane^32 (ds_swizzle)
#pragma unroll
        for (int r = 0; r < 16; ++r) {
            const float ox = __shfl_xor(a[r].x, 32);
            const float oy = __shfl_xor(a[r].y, 32);
            a[r] = rotg(a[r], ox, oy, c, s);
        }
        // qubit 5: lane^16 (ds_swizzle)
#pragma unroll
        for (int r = 0; r < 16; ++r) {
            const float ox = __shfl_xor(a[r].x, 16);
            const float oy = __shfl_xor(a[r].y, 16);
            a[r] = rotg(a[r], ox, oy, c, s);
        }
        // qubit 6: lane^8 via DPP row_ror:8
#pragma unroll
        for (int r = 0; r < 16; ++r) {
            const float ox = dppx<0x128>(a[r].x);
            const float oy = dppx<0x128>(a[r].y);
            a[r] = rotg(a[r], ox, oy, c, s);
        }
        // qubit 7: lane^4 via composed DPP (^7 then ^3)
#pragma unroll
        for (int r = 0; r < 16; ++r) {
            const float ox = dpp_x4(a[r].x);
            const float oy = dpp_x4(a[r].y);
            a[r] = rotg(a[r], ox, oy, c, s);
        }
        // qubit 8: lane^2 via quad_perm
#pragma unroll
        for (int r = 0; r < 16; ++r) {
            const float ox = dppx<0x4E>(a[r].x);
            const float oy = dppx<0x4E>(a[r].y);
            a[r] = rotg(a[r], ox, oy, c, s);
        }
        // qubit 9: lane^1 via quad_perm
#pragma unroll
        for (int r = 0; r < 16; ++r) {
            const float ox = dppx<0xB1>(a[r].x);
            const float oy = dppx<0xB1>(a[r].y);
            a[r] = rotg(a[r], ox, oy, c, s);
        }
    }

    // ---- probabilities & expectation values ----
    float p[16];
#pragma unroll
    for (int r = 0; r < 16; ++r) p[r] = a[r].x * a[r].x + a[r].y * a[r].y;
    float tot = 0.f;
#pragma unroll
    for (int r = 0; r < 16; ++r) tot += p[r];

    if (circ == 0) {
        // actor: all 10 <Z_q>
        float v[10];
#pragma unroll
        for (int q = 0; q < 4; ++q) {
            const int qm = 8 >> q;
            float acc = 0.f;
#pragma unroll
            for (int r = 0; r < 16; ++r) acc += (r & qm) ? -p[r] : p[r];
            v[q] = acc;
        }
#pragma unroll
        for (int k = 0; k < 6; ++k) v[4 + k] = sflip(tot, lb[k]);
#pragma unroll
        for (int q = 0; q < 10; ++q) v[q] = wave_sum(v[q]);

        // epilogue redundantly on all lanes (no divergence), lane 0 stores
        float logits[10], mx = -1e30f;
#pragma unroll
        for (int q = 0; q < 10; ++q) {
            logits[q] = v[q] * osa[q];
            mx = fmaxf(mx, logits[q]);
        }
        float se = 0.f;
#pragma unroll
        for (int q = 0; q < 10; ++q) se += __expf(logits[q] - mx);
        const float lse = __logf(se) + mx;
        float ent = 0.f;
#pragma unroll
        for (int q = 0; q < 10; ++q) {
            const float lp = logits[q] - lse;
            ent -= __expf(lp) * lp;
        }
        if (lane == 0) {
            const int act = action[elem];
            out[elem * 3 + 0] = logits[act] - lse;
            out[elem * 3 + 1] = ent;
        }
    } else {
        // critic: only <Z_0> (r-bit 3)
        float v0 = 0.f;
#pragma unroll
        for (int r = 0; r < 16; ++r) v0 += (r & 8) ? -p[r] : p[r];
        v0 = wave_sum(v0);
        if (lane == 0) out[elem * 3 + 2] = v0 * osc[0];
    }
}

extern "C" void kernel_launch(void* const* d_in, const int* in_sizes, int n_in,
                              void* d_out, int out_size, void* d_ws, size_t ws_size,
                              hipStream_t stream) {
    const float* x      = (const float*)d_in[0];
    const float* isa    = (const float*)d_in[1];
    const float* wa     = (const float*)d_in[2];
    const float* osa    = (const float*)d_in[3];
    const float* isc    = (const float*)d_in[4];
    const float* wc     = (const float*)d_in[5];
    const float* osc    = (const float*)d_in[6];
    const int*   action = (const int*)d_in[7];
    float*       out    = (float*)d_out;

    const int B = in_sizes[7];
    // one block per element: wave 0 = actor, wave 1 = critic; no barriers, no LDS
    ppo_quantum_kernel<<<B, 128, 0, stream>>>(x, isa, wa, osa, isc, wc, osc,
                                              action, out);
}